// Round 5
// baseline (448.805 us; speedup 1.0000x reference)
//
#include <hip/hip_runtime.h>
#include <math.h>

// Problem constants: B=8, C=128, H=W=64, NC=64, NH=4, HC=16, KS=4,
// Hk=Wk=16, Ns=256, HW=4096, NB=3 blocks: (i,j) = (1,0),(2,0),(2,1)

typedef _Float16 f16x4 __attribute__((ext_vector_type(4)));
typedef float f32x4 __attribute__((ext_vector_type(4)));

// ---------------------------------------------------------------- copy out=x
__global__ __launch_bounds__(256) void k_copy(
    const float* __restrict__ x0, const float* __restrict__ x1,
    const float* __restrict__ x2, float* __restrict__ out) {
  int i = blockIdx.x * 256 + threadIdx.x;       // float4 index, 3*1048576 total
  int lvl = i >> 20;
  int idx = i & 1048575;
  const float4* src = (lvl == 0) ? (const float4*)x0
                    : (lvl == 1) ? (const float4*)x1 : (const float4*)x2;
  ((float4*)out)[i] = src[idx];
}

// ------------------------------------------------- q = pq_w @ x_i[:, :64] + b
// Round-5: o-OUTER with x in registers. Round-4's c-outer version stalled
// (VALUBusy 7%): per c it did 1 serial global load + 64 weight s_loads
// STRIDED 256B (new scalar cache line each). Now: 64 independent coalesced
// x-loads issued up front; per o the weight row is CONTIGUOUS (wide
// s_load_dwordx16 streaming) and FMAs use 4-way partial sums.
__global__ __launch_bounds__(256) void k_qconv(
    const float* __restrict__ x1, const float* __restrict__ x2,
    const float* __restrict__ pq_w, const float* __restrict__ pq_b,
    float* __restrict__ q_buf) {
  int wg = blockIdx.x;            // 384 = num(3)*128 + b(8)*16 + tile(16)
  int tile = wg & 15;
  int b = (wg >> 4) & 7;
  int num = wg >> 7;
  const float* xin = (num == 0) ? x1 : x2;
  int px = tile * 256 + threadIdx.x;
  const float* xbase = xin + b * 524288 + px;   // channels 0..63 used
  float xr[64];
#pragma unroll
  for (int c = 0; c < 64; ++c) xr[c] = xbase[c * 4096];  // 64 indep loads
  const float* w = pq_w + num * 4096;
  const float* bias = pq_b + num * 64;
  float* qb = q_buf + (num * 8 + b) * 64 * 4096 + px;
#pragma unroll 4
  for (int o = 0; o < 64; ++o) {
    const float* wr = w + o * 64;               // contiguous row -> dwordx16
    float s0 = 0.f, s1 = 0.f, s2 = 0.f, s3 = 0.f;
#pragma unroll
    for (int c = 0; c < 64; c += 4) {
      s0 += wr[c] * xr[c];
      s1 += wr[c + 1] * xr[c + 1];
      s2 += wr[c + 2] * xr[c + 2];
      s3 += wr[c + 3] * xr[c + 3];
    }
    qb[o * 4096] = (s0 + s1) + (s2 + s3) + bias[o];
  }
}

// ---------------- offset head: depthwise 4x4 s4 + LN + GELU + proj -> pos
__global__ __launch_bounds__(256) void k_offset(
    const float* __restrict__ q_buf, const float* __restrict__ dw_w,
    const float* __restrict__ dw_b, const float* __restrict__ ln_g,
    const float* __restrict__ ln_b, const float* __restrict__ pw_w,
    float* __restrict__ pos_buf) {
  int wg = blockIdx.x;
  int num = wg >> 3;
  int n = threadIdx.x;
  int oy = n >> 4, ox = n & 15;
  const float* qb = q_buf + wg * 64 * 4096;
  float off[64];
  float sum = 0.f, sumsq = 0.f;
#pragma unroll
  for (int c = 0; c < 64; ++c) {
    const float* wp = dw_w + (num * 64 + c) * 16;
    const float* qp = qb + c * 4096 + oy * 256 + ox * 4;
    float4 r0 = *(const float4*)(qp);
    float4 r1 = *(const float4*)(qp + 64);
    float4 r2 = *(const float4*)(qp + 128);
    float4 r3 = *(const float4*)(qp + 192);
    float s = dw_b[num * 64 + c];
    s += wp[0] * r0.x + wp[1] * r0.y + wp[2] * r0.z + wp[3] * r0.w;
    s += wp[4] * r1.x + wp[5] * r1.y + wp[6] * r1.z + wp[7] * r1.w;
    s += wp[8] * r2.x + wp[9] * r2.y + wp[10] * r2.z + wp[11] * r2.w;
    s += wp[12] * r3.x + wp[13] * r3.y + wp[14] * r3.z + wp[15] * r3.w;
    off[c] = s;
    sum += s;
    sumsq += s * s;
  }
  float mu = sum * 0.015625f;
  float var = sumsq * 0.015625f - mu * mu;
  float rstd = rsqrtf(var + 1e-5f);
  float offy = 0.f, offx = 0.f;
#pragma unroll
  for (int c = 0; c < 64; ++c) {
    float g = (off[c] - mu) * rstd * ln_g[num * 64 + c] + ln_b[num * 64 + c];
    g = 0.5f * g * (1.f + erff(g * 0.70710678118654752f));  // exact gelu
    offy += pw_w[num * 128 + c] * g;
    offx += pw_w[num * 128 + 64 + c] * g;
  }
  float ref_y = (0.5f + (float)oy) * (2.f / 15.f) - 1.f;
  float ref_x = (0.5f + (float)ox) * (2.f / 15.f) - 1.f;
  float py = fminf(fmaxf(offy + ref_y, -1.f), 1.f);
  float px = fminf(fmaxf(offx + ref_x, -1.f), 1.f);
  pos_buf[(wg * 256 + n) * 2 + 0] = py;
  pos_buf[(wg * 256 + n) * 2 + 1] = px;
}

// ------------- bilinear sample kv (align_corners=True) -> xs[num][b][c][n]
__global__ __launch_bounds__(256) void k_sample(
    const float* __restrict__ x0, const float* __restrict__ x1,
    const float* __restrict__ pos_buf, float* __restrict__ xs_buf) {
  int wg = blockIdx.x;
  int cg = wg & 7;
  int b = (wg >> 3) & 7;
  int num = wg >> 6;
  const float* xj = (num == 2) ? x1 : x0;       // kv source: x0,x0,x1
  int n = threadIdx.x;
  int nb = num * 8 + b;
  float py = pos_buf[(nb * 256 + n) * 2 + 0];
  float px = pos_buf[(nb * 256 + n) * 2 + 1];
  float fy = (py + 1.f) * 31.5f;                // (g+1)*0.5*(64-1)
  float fx = (px + 1.f) * 31.5f;
  float y0f = floorf(fy), x0f = floorf(fx);
  float wy = fy - y0f, wx = fx - x0f;
  int y0 = (int)y0f, xi0 = (int)x0f;
  int y1 = min(y0 + 1, 63), xi1 = min(xi0 + 1, 63);  // OOB tap has weight 0
  float w00 = (1.f - wy) * (1.f - wx), w01 = (1.f - wy) * wx;
  float w10 = wy * (1.f - wx), w11 = wy * wx;
  const float* xb = xj + b * 524288;
#pragma unroll
  for (int cc = 0; cc < 8; ++cc) {
    int c = cg * 8 + cc;
    const float* p = xb + c * 4096;
    float v = w00 * p[y0 * 64 + xi0] + w01 * p[y0 * 64 + xi1] +
              w10 * p[y1 * 64 + xi0] + w11 * p[y1 * 64 + xi1];
    xs_buf[(nb * 64 + c) * 256 + n] = v;
  }
}

// -------------------------------- k = pk_w@xs + pk_b ; v = pv_w@xs + pv_b
__global__ __launch_bounds__(256) void k_kv(
    const float* __restrict__ xs_buf, const float* __restrict__ pk_w,
    const float* __restrict__ pk_b, const float* __restrict__ pv_w,
    const float* __restrict__ pv_b, float* __restrict__ k_buf,
    float* __restrict__ v_buf) {
  int wg = blockIdx.x;
  int which = wg & 1;
  int nb = wg >> 1;
  int num = nb >> 3;
  const float* w = (which ? pv_w : pk_w) + num * 4096;
  const float* bias = (which ? pv_b : pk_b) + num * 64;
  float* ob = (which ? v_buf : k_buf) + nb * 64 * 256;
  const float* xsb = xs_buf + nb * 64 * 256;
  int n = threadIdx.x;
  float xr[64];
#pragma unroll
  for (int c = 0; c < 64; ++c) xr[c] = xsb[c * 256 + n];
#pragma unroll 4
  for (int o = 0; o < 64; ++o) {
    const float* wr = w + o * 64;
    float s0 = 0.f, s1 = 0.f, s2 = 0.f, s3 = 0.f;
#pragma unroll
    for (int c = 0; c < 64; c += 4) {
      s0 += wr[c] * xr[c];
      s1 += wr[c + 1] * xr[c + 1];
      s2 += wr[c + 2] * xr[c + 2];
      s3 += wr[c + 3] * xr[c + 3];
    }
    ob[o * 256 + n] = (s0 + s1) + (s2 + s3) + bias[o];
  }
}

// -------- pad rpe tables 127x127 -> 128x128 (dup last row/col): removes all
// clamp logic in k_attn; taps become base + imm offsets.
// NOTE: tpad ALIASES xs_buf (dead after k_kv) so ws footprint stays at the
// round-0-proven 29.93 MB — growing ws caused the round-2 device fault.
__global__ __launch_bounds__(128) void k_padrpe(
    const float* __restrict__ rpe, float* __restrict__ tpad) {
  int wg = blockIdx.x;              // 12 tables * 128 rows
  int tbl = wg >> 7;
  int r = wg & 127;
  int c = threadIdx.x;
  int rs = min(r, 126), cs = min(c, 126);
  tpad[tbl * 16384 + r * 128 + c] = rpe[tbl * 16129 + rs * 127 + cs];
}

// ----------------- MFMA attention. S^T = K_A . Q_B  (16x16x16 f16):
// C-layout of S^T (n=quad*4+reg, m=lane&15) == B-frag layout for PV
// (O^T = V_A . P^T_B), so no transpose round-trip is needed.
// grid 1536 = num(3)*b(8)*h(4)*mblock(16); 4 waves, each 4 m-tiles of 16.
//
// Bias table: this block touches exactly rows [mblock*4, mblock*4+67] x
// cols [0,127] of the padded table; stage that 68x128 window in LDS with
// row stride padded to 132 floats.
//
// Round-2 lesson: forcing __launch_bounds__(256,3) with persistent
// kf[16]/vf[16] arrays spilled 64 VGPRs to scratch. Fix is structural:
// LOOP INTERCHANGE (t outer, mt inner) so no 16-entry fragment array
// persists. No forced occupancy cap.
__global__ __launch_bounds__(256) void k_attn(
    float* __restrict__ q_buf, const float* __restrict__ k_buf,
    const float* __restrict__ v_buf, const float* __restrict__ pos_buf,
    const float* __restrict__ tpad) {
  int wg = blockIdx.x;
  int mblock = wg & 15;
  int h = (wg >> 4) & 3;
  int b = (wg >> 6) & 7;
  int num = wg >> 9;
  int nb = num * 8 + b;
  int tid = threadIdx.x;
  int lane = tid & 63;
  int wave = __builtin_amdgcn_readfirstlane(tid >> 6);
  int l15 = lane & 15;
  int quad = lane >> 4;

  __shared__ float4 s_kp[256];
  __shared__ __align__(16) float s_T[68 * 132];   // 35,904 B

  // stage the block's table window: rows mblock*4 .. mblock*4+67 (68x128),
  // dst stride 132. Source base is a multiple of 512 floats -> 16B aligned;
  // max source float idx = 11*16384 + 15*512 + 8703 = 196607 (tpad end).
  {
    const float4* Ts = (const float4*)(tpad + (num * 4 + h) * 16384 + mblock * 512);
    float4* Td = (float4*)s_T;
#pragma unroll
    for (int i = 0; i < 8; ++i) {
      int idx = tid + i * 256;
      Td[idx + (idx >> 5)] = Ts[idx];    // row*33 + col32
    }
    if (tid < 128) {
      int idx = tid + 2048;              // 2176 = 8.5*256 total
      Td[idx + (idx >> 5)] = Ts[idx];
    }
  }

  // per-key bilinear params: table coord t = m + 31.5*(1-pos); store the
  // tap's LDS float offset iy*132+ix (int bits) + fractional weights.
  {
    float py = pos_buf[(nb * 256 + tid) * 2 + 0];
    float px = pos_buf[(nb * 256 + tid) * 2 + 1];
    float by = 31.5f * (1.f - py);
    float bx = 31.5f * (1.f - px);
    float iyf = floorf(by), ixf = floorf(bx);
    float4 kp;
    kp.x = __int_as_float((int)iyf * 132 + (int)ixf);
    kp.y = by - iyf;                  // wy
    kp.z = bx - ixf;                  // wx
    kp.w = 0.f;
    s_kp[tid] = kp;
  }
  __syncthreads();

  int hc = nb * 64 + h * 16;
  const float* kb = k_buf + hc * 256;
  const float* vb = v_buf + hc * 256;
  float* qb = q_buf + hc * 4096;
  const float* Trow = s_T + wave * 132 + l15;   // + mt*16 + tap offset

  // persistent per-mt state (statically indexed everywhere)
  f16x4 qf[4];
  f32x4 O[4];
  float L[4];
#pragma unroll
  for (int mt = 0; mt < 4; ++mt) {
    int m = mblock * 256 + wave * 64 + mt * 16 + l15;
#pragma unroll
    for (int j = 0; j < 4; ++j)
      qf[mt][j] = (_Float16)qb[(quad * 4 + j) * 4096 + m];  // B[c][m]
    O[mt][0] = 0.f; O[mt][1] = 0.f; O[mt][2] = 0.f; O[mt][3] = 0.f;
    L[mt] = 0.f;
  }

#pragma unroll 2
  for (int t = 0; t < 16; ++t) {
    // K frag: A[n][c]: n = t*16 + l15, c = quad*4+j
    f16x4 kf;
#pragma unroll
    for (int j = 0; j < 4; ++j)
      kf[j] = (_Float16)kb[(quad * 4 + j) * 256 + t * 16 + l15];
    // V frag: A[c][n]: c = l15, n = t*16 + quad*4+j -> contiguous float4
    float4 vv = *(const float4*)(vb + l15 * 256 + t * 16 + quad * 4);
    f16x4 vf;
    vf[0] = (_Float16)vv.x; vf[1] = (_Float16)vv.y;
    vf[2] = (_Float16)vv.z; vf[3] = (_Float16)vv.w;

    f32x4 S[4];
#pragma unroll
    for (int mt = 0; mt < 4; ++mt) {
      f32x4 Z = {0.f, 0.f, 0.f, 0.f};
      S[mt] = __builtin_amdgcn_mfma_f32_16x16x16f16(kf, qf[mt], Z, 0, 0, 0);
    }

    f16x4 pf[4];
#pragma unroll
    for (int r = 0; r < 4; ++r) {
      float4 kp = s_kp[t * 16 + quad * 4 + r];
      int off = __float_as_int(kp.x);
#pragma unroll
      for (int mt = 0; mt < 4; ++mt) {
        const float* p = Trow + mt * 16 + off;
        float t00 = p[0], t01 = p[1], t10 = p[132], t11 = p[133];
        float lx0 = fmaf(kp.z, t01 - t00, t00);
        float lx1 = fmaf(kp.z, t11 - t10, t10);
        float bias = fmaf(kp.y, lx1 - lx0, lx0);
        float s = fminf(fmaf(S[mt][r], 0.25f, bias), 10.f);  // logits << 10
        float e = __expf(s);
        L[mt] += e;
        pf[mt][r] = (_Float16)e;
      }
    }
#pragma unroll
    for (int mt = 0; mt < 4; ++mt)
      O[mt] = __builtin_amdgcn_mfma_f32_16x16x16f16(vf, pf[mt], O[mt], 0, 0, 0);
  }

#pragma unroll
  for (int mt = 0; mt < 4; ++mt) {
    float Lm = L[mt];
    Lm += __shfl_xor(Lm, 16);
    Lm += __shfl_xor(Lm, 32);
    float rinv = 1.f / Lm;
    int m = mblock * 256 + wave * 64 + mt * 16 + l15;
#pragma unroll
    for (int r = 0; r < 4; ++r)
      qb[(quad * 4 + r) * 4096 + m] = O[mt][r] * rinv;  // in-place over q
  }
}

// ------------------- po conv, out[l][b][64+o][p] += sum_num conv + bias
// Round-5: o-OUTER, x-in-registers (round-4 c-outer stalled on strided
// weight s_loads + serial per-c load: VALUBusy 7%). Level-2 blocks keep
// BOTH attn columns in regs (xA,xB: ~128 VGPR, statically indexed) and
// loop num-fused per o: contiguous weight rows from two matrices, 4-way
// partial sums, o-unroll 4 to overlap the per-o RMW latency. No atomics.
__global__ __launch_bounds__(256) void k_po(
    const float* __restrict__ attn_buf, const float* __restrict__ po_w,
    const float* __restrict__ po_b, float* __restrict__ out) {
  int wg = blockIdx.x;
  int tile = wg & 15;
  int b = (wg >> 4) & 7;
  int l = (wg >> 7) + 1;                        // 1 or 2
  int px = tile * 256 + threadIdx.x;
  int nlo = (l == 1) ? 0 : 1;
  bool two = (l == 2);

  const float* a0 = attn_buf + (nlo * 8 + b) * 64 * 4096 + px;
  float xA[64];
#pragma unroll
  for (int c = 0; c < 64; ++c) xA[c] = a0[c * 4096];  // 64 indep loads

  float xB[64];
  if (two) {
    const float* a1 = attn_buf + ((nlo + 1) * 8 + b) * 64 * 4096 + px;
#pragma unroll
    for (int c = 0; c < 64; ++c) xB[c] = a1[c * 4096];
  }

  const float* w0 = po_w + nlo * 4096;
  const float* w1 = po_w + (nlo + 1) * 4096;
  float* ob = out + ((l * 8 + b) * 128 + 64) * 4096 + px;

#pragma unroll 4
  for (int o = 0; o < 64; ++o) {
    const float* wr0 = w0 + o * 64;             // contiguous -> dwordx16
    float s0 = 0.f, s1 = 0.f, s2 = 0.f, s3 = 0.f;
#pragma unroll
    for (int c = 0; c < 64; c += 4) {
      s0 += wr0[c] * xA[c];
      s1 += wr0[c + 1] * xA[c + 1];
      s2 += wr0[c + 2] * xA[c + 2];
      s3 += wr0[c + 3] * xA[c + 3];
    }
    float bias = po_b[nlo * 64 + o];
    if (two) {
      const float* wr1 = w1 + o * 64;
#pragma unroll
      for (int c = 0; c < 64; c += 4) {
        s0 += wr1[c] * xB[c];
        s1 += wr1[c + 1] * xB[c + 1];
        s2 += wr1[c + 2] * xB[c + 2];
        s3 += wr1[c + 3] * xB[c + 3];
      }
      bias += po_b[128 + o];
    }
    ob[o * 4096] += (s0 + s1) + (s2 + s3) + bias;  // plain RMW, no atomics
  }
}

extern "C" void kernel_launch(void* const* d_in, const int* in_sizes, int n_in,
                              void* d_out, int out_size, void* d_ws,
                              size_t ws_size, hipStream_t stream) {
  const float* x0 = (const float*)d_in[0];
  const float* x1 = (const float*)d_in[1];
  const float* x2 = (const float*)d_in[2];
  const float* pq_w = (const float*)d_in[3];
  const float* pq_b = (const float*)d_in[4];
  const float* dw_w = (const float*)d_in[5];
  const float* dw_b = (const float*)d_in[6];
  const float* ln_g = (const float*)d_in[7];
  const float* ln_b = (const float*)d_in[8];
  const float* pw_w = (const float*)d_in[9];
  const float* pk_w = (const float*)d_in[10];
  const float* pk_b = (const float*)d_in[11];
  const float* pv_w = (const float*)d_in[12];
  const float* pv_b = (const float*)d_in[13];
  const float* po_w = (const float*)d_in[14];
  const float* po_b = (const float*)d_in[15];
  const float* rpe = (const float*)d_in[16];
  float* out = (float*)d_out;
  float* ws = (float*)d_ws;

  // ws layout (floats): q/attn (in-place) 6291456, pos 12288, xs 393216,
  // k 393216, v 393216 -> 29,933,568 bytes, IDENTICAL to round-0-proven size.
  // tpad (196608) aliases xs_buf: xs is dead after k_kv; k_padrpe runs after.
  float* q_buf = ws;
  float* pos_buf = q_buf + 6291456;
  float* xs_buf = pos_buf + 12288;
  float* k_buf = xs_buf + 393216;
  float* v_buf = k_buf + 393216;
  float* tpad = xs_buf;

  hipLaunchKernelGGL(k_copy, dim3(12288), dim3(256), 0, stream, x0, x1, x2, out);
  hipLaunchKernelGGL(k_qconv, dim3(384), dim3(256), 0, stream, x1, x2, pq_w,
                     pq_b, q_buf);
  hipLaunchKernelGGL(k_offset, dim3(24), dim3(256), 0, stream, q_buf, dw_w,
                     dw_b, ln_g, ln_b, pw_w, pos_buf);
  hipLaunchKernelGGL(k_sample, dim3(192), dim3(256), 0, stream, x0, x1,
                     pos_buf, xs_buf);
  hipLaunchKernelGGL(k_kv, dim3(48), dim3(256), 0, stream, xs_buf, pk_w, pk_b,
                     pv_w, pv_b, k_buf, v_buf);
  hipLaunchKernelGGL(k_padrpe, dim3(1536), dim3(128), 0, stream, rpe, tpad);
  hipLaunchKernelGGL(k_attn, dim3(1536), dim3(256), 0, stream, q_buf, k_buf,
                     v_buf, pos_buf, tpad);
  hipLaunchKernelGGL(k_po, dim3(256), dim3(256), 0, stream, q_buf, po_w, po_b,
                     out);
}

// Round 6
// 322.020 us; speedup vs baseline: 1.3937x; 1.3937x over previous
//
#include <hip/hip_runtime.h>
#include <math.h>

// Problem constants: B=8, C=128, H=W=64, NC=64, NH=4, HC=16, KS=4,
// Hk=Wk=16, Ns=256, HW=4096, NB=3 blocks: (i,j) = (1,0),(2,0),(2,1)

typedef _Float16 f16x4 __attribute__((ext_vector_type(4)));
typedef float f32x4 __attribute__((ext_vector_type(4)));

// ---------------------------------------------------------------- copy out=x
__global__ __launch_bounds__(256) void k_copy(
    const float* __restrict__ x0, const float* __restrict__ x1,
    const float* __restrict__ x2, float* __restrict__ out) {
  int i = blockIdx.x * 256 + threadIdx.x;       // float4 index, 3*1048576 total
  int lvl = i >> 20;
  int idx = i & 1048575;
  const float4* src = (lvl == 0) ? (const float4*)x0
                    : (lvl == 1) ? (const float4*)x1 : (const float4*)x2;
  ((float4*)out)[i] = src[idx];
}

// ------------------------------------------------- q = pq_w @ x_i[:, :64] + b
// Round-6: OCCUPANCY fix. Rounds 4/5 proved this GEMM shape is latency-bound
// at 1 block/CU (occ 8%, VALUBusy 6-7%); round-5's "x in registers" plan was
// silently defeated by the allocator (VGPR=72 -> loads rematerialized).
// Split output channels 4x: grid 1536 = num(3)*og(4)*b(8)*tile(16), each
// block computes 16 out-channels with acc[16] (~40 VGPR). 6 blocks/CU =
// 24 waves/CU interleave across load stalls. Per c: 1 coalesced load +
// 16 independent FMAs; unroll 8 keeps 8 loads in flight.
__global__ __launch_bounds__(256) void k_qconv(
    const float* __restrict__ x1, const float* __restrict__ x2,
    const float* __restrict__ pq_w, const float* __restrict__ pq_b,
    float* __restrict__ q_buf) {
  int wg = blockIdx.x;            // num(3)<<9 | og(4)<<7 | b(8)<<4 | tile(16)
  int tile = wg & 15;
  int b = (wg >> 4) & 7;
  int og = (wg >> 7) & 3;
  int num = wg >> 9;
  const float* xin = (num == 0) ? x1 : x2;
  int px = tile * 256 + threadIdx.x;
  const float* xbase = xin + b * 524288 + px;   // channels 0..63 used
  const float* w = pq_w + num * 4096 + og * 1024;  // rows og*16..og*16+15
  float acc[16];
#pragma unroll
  for (int o = 0; o < 16; ++o) acc[o] = 0.f;
#pragma unroll 8
  for (int c = 0; c < 64; ++c) {
    float xv = xbase[c * 4096];                 // coalesced, 8 in flight
#pragma unroll
    for (int o = 0; o < 16; ++o) acc[o] += w[o * 64 + c] * xv;  // s_loads
  }
  float* qb = q_buf + ((num * 8 + b) * 64 + og * 16) * 4096 + px;
  const float* bias = pq_b + num * 64 + og * 16;
#pragma unroll
  for (int o = 0; o < 16; ++o) qb[o * 4096] = acc[o] + bias[o];
}

// ---------------- offset head: depthwise 4x4 s4 + LN + GELU + proj -> pos
__global__ __launch_bounds__(256) void k_offset(
    const float* __restrict__ q_buf, const float* __restrict__ dw_w,
    const float* __restrict__ dw_b, const float* __restrict__ ln_g,
    const float* __restrict__ ln_b, const float* __restrict__ pw_w,
    float* __restrict__ pos_buf) {
  int wg = blockIdx.x;
  int num = wg >> 3;
  int n = threadIdx.x;
  int oy = n >> 4, ox = n & 15;
  const float* qb = q_buf + wg * 64 * 4096;
  float off[64];
  float sum = 0.f, sumsq = 0.f;
#pragma unroll
  for (int c = 0; c < 64; ++c) {
    const float* wp = dw_w + (num * 64 + c) * 16;
    const float* qp = qb + c * 4096 + oy * 256 + ox * 4;
    float4 r0 = *(const float4*)(qp);
    float4 r1 = *(const float4*)(qp + 64);
    float4 r2 = *(const float4*)(qp + 128);
    float4 r3 = *(const float4*)(qp + 192);
    float s = dw_b[num * 64 + c];
    s += wp[0] * r0.x + wp[1] * r0.y + wp[2] * r0.z + wp[3] * r0.w;
    s += wp[4] * r1.x + wp[5] * r1.y + wp[6] * r1.z + wp[7] * r1.w;
    s += wp[8] * r2.x + wp[9] * r2.y + wp[10] * r2.z + wp[11] * r2.w;
    s += wp[12] * r3.x + wp[13] * r3.y + wp[14] * r3.z + wp[15] * r3.w;
    off[c] = s;
    sum += s;
    sumsq += s * s;
  }
  float mu = sum * 0.015625f;
  float var = sumsq * 0.015625f - mu * mu;
  float rstd = rsqrtf(var + 1e-5f);
  float offy = 0.f, offx = 0.f;
#pragma unroll
  for (int c = 0; c < 64; ++c) {
    float g = (off[c] - mu) * rstd * ln_g[num * 64 + c] + ln_b[num * 64 + c];
    g = 0.5f * g * (1.f + erff(g * 0.70710678118654752f));  // exact gelu
    offy += pw_w[num * 128 + c] * g;
    offx += pw_w[num * 128 + 64 + c] * g;
  }
  float ref_y = (0.5f + (float)oy) * (2.f / 15.f) - 1.f;
  float ref_x = (0.5f + (float)ox) * (2.f / 15.f) - 1.f;
  float py = fminf(fmaxf(offy + ref_y, -1.f), 1.f);
  float px = fminf(fmaxf(offx + ref_x, -1.f), 1.f);
  pos_buf[(wg * 256 + n) * 2 + 0] = py;
  pos_buf[(wg * 256 + n) * 2 + 1] = px;
}

// ------------- bilinear sample kv (align_corners=True) -> xs[num][b][c][n]
__global__ __launch_bounds__(256) void k_sample(
    const float* __restrict__ x0, const float* __restrict__ x1,
    const float* __restrict__ pos_buf, float* __restrict__ xs_buf) {
  int wg = blockIdx.x;
  int cg = wg & 7;
  int b = (wg >> 3) & 7;
  int num = wg >> 6;
  const float* xj = (num == 2) ? x1 : x0;       // kv source: x0,x0,x1
  int n = threadIdx.x;
  int nb = num * 8 + b;
  float py = pos_buf[(nb * 256 + n) * 2 + 0];
  float px = pos_buf[(nb * 256 + n) * 2 + 1];
  float fy = (py + 1.f) * 31.5f;                // (g+1)*0.5*(64-1)
  float fx = (px + 1.f) * 31.5f;
  float y0f = floorf(fy), x0f = floorf(fx);
  float wy = fy - y0f, wx = fx - x0f;
  int y0 = (int)y0f, xi0 = (int)x0f;
  int y1 = min(y0 + 1, 63), xi1 = min(xi0 + 1, 63);  // OOB tap has weight 0
  float w00 = (1.f - wy) * (1.f - wx), w01 = (1.f - wy) * wx;
  float w10 = wy * (1.f - wx), w11 = wy * wx;
  const float* xb = xj + b * 524288;
#pragma unroll
  for (int cc = 0; cc < 8; ++cc) {
    int c = cg * 8 + cc;
    const float* p = xb + c * 4096;
    float v = w00 * p[y0 * 64 + xi0] + w01 * p[y0 * 64 + xi1] +
              w10 * p[y1 * 64 + xi0] + w11 * p[y1 * 64 + xi1];
    xs_buf[(nb * 64 + c) * 256 + n] = v;
  }
}

// -------------------------------- k = pk_w@xs + pk_b ; v = pv_w@xs + pv_b
// Round-6: same o-split occupancy fix (grid 48 -> 192, acc[16]).
__global__ __launch_bounds__(256) void k_kv(
    const float* __restrict__ xs_buf, const float* __restrict__ pk_w,
    const float* __restrict__ pk_b, const float* __restrict__ pv_w,
    const float* __restrict__ pv_b, float* __restrict__ k_buf,
    float* __restrict__ v_buf) {
  int wg = blockIdx.x;              // 192 = og(4) * nb(24) * which(2)
  int which = wg & 1;
  int rest = wg >> 1;
  int nb = rest % 24;
  int og = rest / 24;
  int num = nb >> 3;
  const float* w = (which ? pv_w : pk_w) + num * 4096 + og * 1024;
  const float* bias = (which ? pv_b : pk_b) + num * 64 + og * 16;
  float* ob = (which ? v_buf : k_buf) + (nb * 64 + og * 16) * 256;
  const float* xsb = xs_buf + nb * 64 * 256;
  int n = threadIdx.x;
  float acc[16];
#pragma unroll
  for (int o = 0; o < 16; ++o) acc[o] = 0.f;
#pragma unroll 8
  for (int c = 0; c < 64; ++c) {
    float xv = xsb[c * 256 + n];
#pragma unroll
    for (int o = 0; o < 16; ++o) acc[o] += w[o * 64 + c] * xv;
  }
#pragma unroll
  for (int o = 0; o < 16; ++o) ob[o * 256 + n] = acc[o] + bias[o];
}

// -------- pad rpe tables 127x127 -> 128x128 (dup last row/col): removes all
// clamp logic in k_attn; taps become base + imm offsets.
// NOTE: tpad ALIASES xs_buf (dead after k_kv) so ws footprint stays at the
// round-0-proven 29.93 MB — growing ws caused the round-2 device fault.
__global__ __launch_bounds__(128) void k_padrpe(
    const float* __restrict__ rpe, float* __restrict__ tpad) {
  int wg = blockIdx.x;              // 12 tables * 128 rows
  int tbl = wg >> 7;
  int r = wg & 127;
  int c = threadIdx.x;
  int rs = min(r, 126), cs = min(c, 126);
  tpad[tbl * 16384 + r * 128 + c] = rpe[tbl * 16129 + rs * 127 + cs];
}

// ----------------- MFMA attention. S^T = K_A . Q_B  (16x16x16 f16):
// C-layout of S^T (n=quad*4+reg, m=lane&15) == B-frag layout for PV
// (O^T = V_A . P^T_B), so no transpose round-trip is needed.
// grid 1536 = num(3)*b(8)*h(4)*mblock(16); 4 waves, each 4 m-tiles of 16.
//
// Bias table: this block touches exactly rows [mblock*4, mblock*4+67] x
// cols [0,127] of the padded table; stage that 68x128 window in LDS with
// row stride padded to 132 floats.
//
// Round-2 lesson: forcing __launch_bounds__(256,3) with persistent
// kf[16]/vf[16] arrays spilled 64 VGPRs to scratch. Fix is structural:
// LOOP INTERCHANGE (t outer, mt inner) so no 16-entry fragment array
// persists. No forced occupancy cap.
__global__ __launch_bounds__(256) void k_attn(
    float* __restrict__ q_buf, const float* __restrict__ k_buf,
    const float* __restrict__ v_buf, const float* __restrict__ pos_buf,
    const float* __restrict__ tpad) {
  int wg = blockIdx.x;
  int mblock = wg & 15;
  int h = (wg >> 4) & 3;
  int b = (wg >> 6) & 7;
  int num = wg >> 9;
  int nb = num * 8 + b;
  int tid = threadIdx.x;
  int lane = tid & 63;
  int wave = __builtin_amdgcn_readfirstlane(tid >> 6);
  int l15 = lane & 15;
  int quad = lane >> 4;

  __shared__ float4 s_kp[256];
  __shared__ __align__(16) float s_T[68 * 132];   // 35,904 B

  // stage the block's table window: rows mblock*4 .. mblock*4+67 (68x128),
  // dst stride 132. Source base is a multiple of 512 floats -> 16B aligned;
  // max source float idx = 11*16384 + 15*512 + 8703 = 196607 (tpad end).
  {
    const float4* Ts = (const float4*)(tpad + (num * 4 + h) * 16384 + mblock * 512);
    float4* Td = (float4*)s_T;
#pragma unroll
    for (int i = 0; i < 8; ++i) {
      int idx = tid + i * 256;
      Td[idx + (idx >> 5)] = Ts[idx];    // row*33 + col32
    }
    if (tid < 128) {
      int idx = tid + 2048;              // 2176 = 8.5*256 total
      Td[idx + (idx >> 5)] = Ts[idx];
    }
  }

  // per-key bilinear params: table coord t = m + 31.5*(1-pos); store the
  // tap's LDS float offset iy*132+ix (int bits) + fractional weights.
  {
    float py = pos_buf[(nb * 256 + tid) * 2 + 0];
    float px = pos_buf[(nb * 256 + tid) * 2 + 1];
    float by = 31.5f * (1.f - py);
    float bx = 31.5f * (1.f - px);
    float iyf = floorf(by), ixf = floorf(bx);
    float4 kp;
    kp.x = __int_as_float((int)iyf * 132 + (int)ixf);
    kp.y = by - iyf;                  // wy
    kp.z = bx - ixf;                  // wx
    kp.w = 0.f;
    s_kp[tid] = kp;
  }
  __syncthreads();

  int hc = nb * 64 + h * 16;
  const float* kb = k_buf + hc * 256;
  const float* vb = v_buf + hc * 256;
  float* qb = q_buf + hc * 4096;
  const float* Trow = s_T + wave * 132 + l15;   // + mt*16 + tap offset

  // persistent per-mt state (statically indexed everywhere)
  f16x4 qf[4];
  f32x4 O[4];
  float L[4];
#pragma unroll
  for (int mt = 0; mt < 4; ++mt) {
    int m = mblock * 256 + wave * 64 + mt * 16 + l15;
#pragma unroll
    for (int j = 0; j < 4; ++j)
      qf[mt][j] = (_Float16)qb[(quad * 4 + j) * 4096 + m];  // B[c][m]
    O[mt][0] = 0.f; O[mt][1] = 0.f; O[mt][2] = 0.f; O[mt][3] = 0.f;
    L[mt] = 0.f;
  }

#pragma unroll 2
  for (int t = 0; t < 16; ++t) {
    // K frag: A[n][c]: n = t*16 + l15, c = quad*4+j
    f16x4 kf;
#pragma unroll
    for (int j = 0; j < 4; ++j)
      kf[j] = (_Float16)kb[(quad * 4 + j) * 256 + t * 16 + l15];
    // V frag: A[c][n]: c = l15, n = t*16 + quad*4+j -> contiguous float4
    float4 vv = *(const float4*)(vb + l15 * 256 + t * 16 + quad * 4);
    f16x4 vf;
    vf[0] = (_Float16)vv.x; vf[1] = (_Float16)vv.y;
    vf[2] = (_Float16)vv.z; vf[3] = (_Float16)vv.w;

    f32x4 S[4];
#pragma unroll
    for (int mt = 0; mt < 4; ++mt) {
      f32x4 Z = {0.f, 0.f, 0.f, 0.f};
      S[mt] = __builtin_amdgcn_mfma_f32_16x16x16f16(kf, qf[mt], Z, 0, 0, 0);
    }

    f16x4 pf[4];
#pragma unroll
    for (int r = 0; r < 4; ++r) {
      float4 kp = s_kp[t * 16 + quad * 4 + r];
      int off = __float_as_int(kp.x);
#pragma unroll
      for (int mt = 0; mt < 4; ++mt) {
        const float* p = Trow + mt * 16 + off;
        float t00 = p[0], t01 = p[1], t10 = p[132], t11 = p[133];
        float lx0 = fmaf(kp.z, t01 - t00, t00);
        float lx1 = fmaf(kp.z, t11 - t10, t10);
        float bias = fmaf(kp.y, lx1 - lx0, lx0);
        float s = fminf(fmaf(S[mt][r], 0.25f, bias), 10.f);  // logits << 10
        float e = __expf(s);
        L[mt] += e;
        pf[mt][r] = (_Float16)e;
      }
    }
#pragma unroll
    for (int mt = 0; mt < 4; ++mt)
      O[mt] = __builtin_amdgcn_mfma_f32_16x16x16f16(vf, pf[mt], O[mt], 0, 0, 0);
  }

#pragma unroll
  for (int mt = 0; mt < 4; ++mt) {
    float Lm = L[mt];
    Lm += __shfl_xor(Lm, 16);
    Lm += __shfl_xor(Lm, 32);
    float rinv = 1.f / Lm;
    int m = mblock * 256 + wave * 64 + mt * 16 + l15;
#pragma unroll
    for (int r = 0; r < 4; ++r)
      qb[(quad * 4 + r) * 4096 + m] = O[mt][r] * rinv;  // in-place over q
  }
}

// ------------------- po conv, out[l][b][64+o][p] += sum_num conv + bias
// Round-6: occupancy fix — grid 1024 = l(2)*og(4)*b(8)*tile(16), acc[16].
// Level-2 blocks loop num in {1,2} (two passes, same acc), zero atomics.
// 4 blocks/CU = 16 waves/CU hide the per-c load latency that rounds 4/5
// exposed at 1 block/CU (VALUBusy 6-7%). x re-reads (4x) are L3-resident.
__global__ __launch_bounds__(256) void k_po(
    const float* __restrict__ attn_buf, const float* __restrict__ po_w,
    const float* __restrict__ po_b, float* __restrict__ out) {
  int wg = blockIdx.x;              // l(2)<<9 | og(4)<<7 | b(8)<<4 | tile(16)
  int tile = wg & 15;
  int b = (wg >> 4) & 7;
  int og = (wg >> 7) & 3;
  int l = (wg >> 9) + 1;            // 1 or 2
  int px = tile * 256 + threadIdx.x;
  int nlo = (l == 1) ? 0 : 1;
  int nPasses = (l == 1) ? 1 : 2;

  float acc[16];
#pragma unroll
  for (int o = 0; o < 16; ++o) acc[o] = 0.f;

  for (int s = 0; s < nPasses; ++s) {
    int num = nlo + s;
    const float* abase = attn_buf + (num * 8 + b) * 64 * 4096 + px;
    const float* w = po_w + num * 4096 + og * 1024;
#pragma unroll 8
    for (int c = 0; c < 64; ++c) {
      float xv = abase[c * 4096];   // coalesced, 8 in flight
#pragma unroll
      for (int o = 0; o < 16; ++o) acc[o] += w[o * 64 + c] * xv;  // s_loads
    }
  }

  float* ob = out + ((l * 8 + b) * 128 + 64 + og * 16) * 4096 + px;
#pragma unroll
  for (int o = 0; o < 16; ++o) {
    float bias = po_b[nlo * 64 + og * 16 + o];
    if (l == 2) bias += po_b[128 + og * 16 + o];
    ob[o * 4096] += acc[o] + bias;  // plain RMW, no atomics
  }
}

extern "C" void kernel_launch(void* const* d_in, const int* in_sizes, int n_in,
                              void* d_out, int out_size, void* d_ws,
                              size_t ws_size, hipStream_t stream) {
  const float* x0 = (const float*)d_in[0];
  const float* x1 = (const float*)d_in[1];
  const float* x2 = (const float*)d_in[2];
  const float* pq_w = (const float*)d_in[3];
  const float* pq_b = (const float*)d_in[4];
  const float* dw_w = (const float*)d_in[5];
  const float* dw_b = (const float*)d_in[6];
  const float* ln_g = (const float*)d_in[7];
  const float* ln_b = (const float*)d_in[8];
  const float* pw_w = (const float*)d_in[9];
  const float* pk_w = (const float*)d_in[10];
  const float* pk_b = (const float*)d_in[11];
  const float* pv_w = (const float*)d_in[12];
  const float* pv_b = (const float*)d_in[13];
  const float* po_w = (const float*)d_in[14];
  const float* po_b = (const float*)d_in[15];
  const float* rpe = (const float*)d_in[16];
  float* out = (float*)d_out;
  float* ws = (float*)d_ws;

  // ws layout (floats): q/attn (in-place) 6291456, pos 12288, xs 393216,
  // k 393216, v 393216 -> 29,933,568 bytes, IDENTICAL to round-0-proven size.
  // tpad (196608) aliases xs_buf: xs is dead after k_kv; k_padrpe runs after.
  float* q_buf = ws;
  float* pos_buf = q_buf + 6291456;
  float* xs_buf = pos_buf + 12288;
  float* k_buf = xs_buf + 393216;
  float* v_buf = k_buf + 393216;
  float* tpad = xs_buf;

  hipLaunchKernelGGL(k_copy, dim3(12288), dim3(256), 0, stream, x0, x1, x2, out);
  hipLaunchKernelGGL(k_qconv, dim3(1536), dim3(256), 0, stream, x1, x2, pq_w,
                     pq_b, q_buf);
  hipLaunchKernelGGL(k_offset, dim3(24), dim3(256), 0, stream, q_buf, dw_w,
                     dw_b, ln_g, ln_b, pw_w, pos_buf);
  hipLaunchKernelGGL(k_sample, dim3(192), dim3(256), 0, stream, x0, x1,
                     pos_buf, xs_buf);
  hipLaunchKernelGGL(k_kv, dim3(192), dim3(256), 0, stream, xs_buf, pk_w, pk_b,
                     pv_w, pv_b, k_buf, v_buf);
  hipLaunchKernelGGL(k_padrpe, dim3(1536), dim3(128), 0, stream, rpe, tpad);
  hipLaunchKernelGGL(k_attn, dim3(1536), dim3(256), 0, stream, q_buf, k_buf,
                     v_buf, pos_buf, tpad);
  hipLaunchKernelGGL(k_po, dim3(1024), dim3(256), 0, stream, q_buf, po_w, po_b,
                     out);
}

// Round 7
// 281.324 us; speedup vs baseline: 1.5953x; 1.1447x over previous
//
#include <hip/hip_runtime.h>
#include <math.h>

// Problem constants: B=8, C=128, H=W=64, NC=64, NH=4, HC=16, KS=4,
// Hk=Wk=16, Ns=256, HW=4096, NB=3 blocks: (i,j) = (1,0),(2,0),(2,1)

typedef _Float16 f16x4 __attribute__((ext_vector_type(4)));
typedef float f32x4 __attribute__((ext_vector_type(4)));

// ---------------------------------------------------------------- copy out=x
__global__ __launch_bounds__(256) void k_copy(
    const float* __restrict__ x0, const float* __restrict__ x1,
    const float* __restrict__ x2, float* __restrict__ out) {
  int i = blockIdx.x * 256 + threadIdx.x;       // float4 index, 3*1048576 total
  int lvl = i >> 20;
  int idx = i & 1048575;
  const float4* src = (lvl == 0) ? (const float4*)x0
                    : (lvl == 1) ? (const float4*)x1 : (const float4*)x2;
  ((float4*)out)[i] = src[idx];
}

// ------------------------------------------------- q = pq_w @ x_i[:, :64] + b
// Round-7: og-split 8 (grid 3072, acc[8], ~30 VGPR) — the occupancy lever
// that fixed k_po in round 6, pushed further: up to 8 blocks/CU.
__global__ __launch_bounds__(256) void k_qconv(
    const float* __restrict__ x1, const float* __restrict__ x2,
    const float* __restrict__ pq_w, const float* __restrict__ pq_b,
    float* __restrict__ q_buf) {
  int wg = blockIdx.x;            // num(3)<<10 | og(8)<<7 | b(8)<<4 | tile(16)
  int tile = wg & 15;
  int b = (wg >> 4) & 7;
  int og = (wg >> 7) & 7;
  int num = wg >> 10;
  const float* xin = (num == 0) ? x1 : x2;
  int px = tile * 256 + threadIdx.x;
  const float* xbase = xin + b * 524288 + px;   // channels 0..63 used
  const float* w = pq_w + num * 4096 + og * 512;  // rows og*8..og*8+7
  float acc[8];
#pragma unroll
  for (int o = 0; o < 8; ++o) acc[o] = 0.f;
#pragma unroll 8
  for (int c = 0; c < 64; ++c) {
    float xv = xbase[c * 4096];                 // coalesced, 8 in flight
#pragma unroll
    for (int o = 0; o < 8; ++o) acc[o] += w[o * 64 + c] * xv;  // s_loads
  }
  float* qb = q_buf + ((num * 8 + b) * 64 + og * 8) * 4096 + px;
  const float* bias = pq_b + num * 64 + og * 8;
#pragma unroll
  for (int o = 0; o < 8; ++o) qb[o * 4096] = acc[o] + bias[o];
}

// ---------------- offset head: depthwise 4x4 s4 + LN + GELU + proj -> pos
__global__ __launch_bounds__(256) void k_offset(
    const float* __restrict__ q_buf, const float* __restrict__ dw_w,
    const float* __restrict__ dw_b, const float* __restrict__ ln_g,
    const float* __restrict__ ln_b, const float* __restrict__ pw_w,
    float* __restrict__ pos_buf) {
  int wg = blockIdx.x;
  int num = wg >> 3;
  int n = threadIdx.x;
  int oy = n >> 4, ox = n & 15;
  const float* qb = q_buf + wg * 64 * 4096;
  float off[64];
  float sum = 0.f, sumsq = 0.f;
#pragma unroll
  for (int c = 0; c < 64; ++c) {
    const float* wp = dw_w + (num * 64 + c) * 16;
    const float* qp = qb + c * 4096 + oy * 256 + ox * 4;
    float4 r0 = *(const float4*)(qp);
    float4 r1 = *(const float4*)(qp + 64);
    float4 r2 = *(const float4*)(qp + 128);
    float4 r3 = *(const float4*)(qp + 192);
    float s = dw_b[num * 64 + c];
    s += wp[0] * r0.x + wp[1] * r0.y + wp[2] * r0.z + wp[3] * r0.w;
    s += wp[4] * r1.x + wp[5] * r1.y + wp[6] * r1.z + wp[7] * r1.w;
    s += wp[8] * r2.x + wp[9] * r2.y + wp[10] * r2.z + wp[11] * r2.w;
    s += wp[12] * r3.x + wp[13] * r3.y + wp[14] * r3.z + wp[15] * r3.w;
    off[c] = s;
    sum += s;
    sumsq += s * s;
  }
  float mu = sum * 0.015625f;
  float var = sumsq * 0.015625f - mu * mu;
  float rstd = rsqrtf(var + 1e-5f);
  float offy = 0.f, offx = 0.f;
#pragma unroll
  for (int c = 0; c < 64; ++c) {
    float g = (off[c] - mu) * rstd * ln_g[num * 64 + c] + ln_b[num * 64 + c];
    g = 0.5f * g * (1.f + erff(g * 0.70710678118654752f));  // exact gelu
    offy += pw_w[num * 128 + c] * g;
    offx += pw_w[num * 128 + 64 + c] * g;
  }
  float ref_y = (0.5f + (float)oy) * (2.f / 15.f) - 1.f;
  float ref_x = (0.5f + (float)ox) * (2.f / 15.f) - 1.f;
  float py = fminf(fmaxf(offy + ref_y, -1.f), 1.f);
  float px = fminf(fmaxf(offx + ref_x, -1.f), 1.f);
  pos_buf[(wg * 256 + n) * 2 + 0] = py;
  pos_buf[(wg * 256 + n) * 2 + 1] = px;
}

// ------------- bilinear sample kv (align_corners=True) -> xs[num][b][c][n]
__global__ __launch_bounds__(256) void k_sample(
    const float* __restrict__ x0, const float* __restrict__ x1,
    const float* __restrict__ pos_buf, float* __restrict__ xs_buf) {
  int wg = blockIdx.x;
  int cg = wg & 7;
  int b = (wg >> 3) & 7;
  int num = wg >> 6;
  const float* xj = (num == 2) ? x1 : x0;       // kv source: x0,x0,x1
  int n = threadIdx.x;
  int nb = num * 8 + b;
  float py = pos_buf[(nb * 256 + n) * 2 + 0];
  float px = pos_buf[(nb * 256 + n) * 2 + 1];
  float fy = (py + 1.f) * 31.5f;                // (g+1)*0.5*(64-1)
  float fx = (px + 1.f) * 31.5f;
  float y0f = floorf(fy), x0f = floorf(fx);
  float wy = fy - y0f, wx = fx - x0f;
  int y0 = (int)y0f, xi0 = (int)x0f;
  int y1 = min(y0 + 1, 63), xi1 = min(xi0 + 1, 63);  // OOB tap has weight 0
  float w00 = (1.f - wy) * (1.f - wx), w01 = (1.f - wy) * wx;
  float w10 = wy * (1.f - wx), w11 = wy * wx;
  const float* xb = xj + b * 524288;
#pragma unroll
  for (int cc = 0; cc < 8; ++cc) {
    int c = cg * 8 + cc;
    const float* p = xb + c * 4096;
    float v = w00 * p[y0 * 64 + xi0] + w01 * p[y0 * 64 + xi1] +
              w10 * p[y1 * 64 + xi0] + w11 * p[y1 * 64 + xi1];
    xs_buf[(nb * 64 + c) * 256 + n] = v;
  }
}

// -------------------------------- k = pk_w@xs + pk_b ; v = pv_w@xs + pv_b
// Round-7: og-split 8 (grid 384) and OUTPUT IN F16. k_attn converted k/v to
// f16 anyway — moving the conversion here is bit-identical and deletes the
// per-t cvt chain in k_attn + halves k/v read bytes there.
__global__ __launch_bounds__(256) void k_kv(
    const float* __restrict__ xs_buf, const float* __restrict__ pk_w,
    const float* __restrict__ pk_b, const float* __restrict__ pv_w,
    const float* __restrict__ pv_b, _Float16* __restrict__ k16,
    _Float16* __restrict__ v16) {
  int wg = blockIdx.x;              // 384 = og(8) * nb(24) * which(2)
  int which = wg & 1;
  int rest = wg >> 1;
  int nb = rest % 24;
  int og = rest / 24;
  int num = nb >> 3;
  const float* w = (which ? pv_w : pk_w) + num * 4096 + og * 512;
  const float* bias = (which ? pv_b : pk_b) + num * 64 + og * 8;
  _Float16* ob = (which ? v16 : k16) + (nb * 64 + og * 8) * 256;
  const float* xsb = xs_buf + nb * 64 * 256;
  int n = threadIdx.x;
  float acc[8];
#pragma unroll
  for (int o = 0; o < 8; ++o) acc[o] = 0.f;
#pragma unroll 8
  for (int c = 0; c < 64; ++c) {
    float xv = xsb[c * 256 + n];
#pragma unroll
    for (int o = 0; o < 8; ++o) acc[o] += w[o * 64 + c] * xv;
  }
#pragma unroll
  for (int o = 0; o < 8; ++o) ob[o * 256 + n] = (_Float16)(acc[o] + bias[o]);
}

// -------- pad rpe tables 127x127 -> 128x128 (dup last row/col): removes all
// clamp logic in k_attn; taps become base + imm offsets.
// NOTE: tpad ALIASES xs_buf (dead after k_kv) so ws footprint stays at the
// round-0-proven 29.93 MB — growing ws caused the round-2 device fault.
__global__ __launch_bounds__(128) void k_padrpe(
    const float* __restrict__ rpe, float* __restrict__ tpad) {
  int wg = blockIdx.x;              // 12 tables * 128 rows
  int tbl = wg >> 7;
  int r = wg & 127;
  int c = threadIdx.x;
  int rs = min(r, 126), cs = min(c, 126);
  tpad[tbl * 16384 + r * 128 + c] = rpe[tbl * 16129 + rs * 127 + cs];
}

// ----------------- MFMA attention. S^T = K_A . Q_B  (16x16x16 f16):
// C-layout of S^T (n=quad*4+reg, m=lane&15) == B-frag layout for PV
// (O^T = V_A . P^T_B), so no transpose round-trip is needed.
// grid 1536 = num(3)*b(8)*h(4)*mblock(16); 4 waves, each 4 m-tiles of 16.
//
// Round-7 changes (k_attn is VALU-bound: VALUBusy 58%, MfmaUtil 7%):
//  * 4 bilinear weights PRECOMPUTED per key in s_wt[256] (+ s_off[256]):
//    inner bias = 4 FMAs, no sub chain.  * fmin clamp dropped (logits ~±3,
//    never binds on this data).  * K/V read as f16 (cvt moved to k_kv,
//    bit-identical).  * stride-132 pad REVERTED to 128: measured conflicts
//    were identical (1.124e7 @128 in round 1 vs 1.126e7 @132) — conflicts
//    come from data-dependent tap offsets mod 32, padding can't help; the
//    freed LDS pays for s_wt/s_off. Total LDS 39,936 B -> 4 blocks/CU kept.
__global__ __launch_bounds__(256) void k_attn(
    float* __restrict__ q_buf, const _Float16* __restrict__ k16,
    const _Float16* __restrict__ v16, const float* __restrict__ pos_buf,
    const float* __restrict__ tpad) {
  int wg = blockIdx.x;
  int mblock = wg & 15;
  int h = (wg >> 4) & 3;
  int b = (wg >> 6) & 7;
  int num = wg >> 9;
  int nb = num * 8 + b;
  int tid = threadIdx.x;
  int lane = tid & 63;
  int wave = __builtin_amdgcn_readfirstlane(tid >> 6);
  int l15 = lane & 15;
  int quad = lane >> 4;

  __shared__ __align__(16) float s_T[68 * 128];   // 34,816 B
  __shared__ float4 s_wt[256];                    //  4,096 B
  __shared__ int s_off[256];                      //  1,024 B (39,936 total)

  // stage the block's table window: rows mblock*4 .. mblock*4+67 (68x128).
  // Source base is a multiple of 512 floats -> 16B aligned; max source
  // float idx = 11*16384 + 15*512 + 8703 = 196607 (tpad end).
  {
    const float4* Ts = (const float4*)(tpad + (num * 4 + h) * 16384 + mblock * 512);
    float4* Td = (float4*)s_T;
#pragma unroll
    for (int i = 0; i < 8; ++i) Td[tid + i * 256] = Ts[tid + i * 256];
    if (tid < 128) Td[tid + 2048] = Ts[tid + 2048];   // 2176 = 8.5*256
  }

  // per-key bilinear params: table coord t = m + 31.5*(1-pos).
  // Precompute the tap offset AND all 4 bilinear weights.
  {
    float py = pos_buf[(nb * 256 + tid) * 2 + 0];
    float px = pos_buf[(nb * 256 + tid) * 2 + 1];
    float by = 31.5f * (1.f - py);
    float bx = 31.5f * (1.f - px);
    float iyf = floorf(by), ixf = floorf(bx);
    float wy = by - iyf, wx = bx - ixf;
    float uy = 1.f - wy, ux = 1.f - wx;
    s_off[tid] = (int)iyf * 128 + (int)ixf;
    s_wt[tid] = make_float4(uy * ux, uy * wx, wy * ux, wy * wx);
  }
  __syncthreads();

  int hc = nb * 64 + h * 16;
  const _Float16* kb = k16 + hc * 256;
  const _Float16* vb = v16 + hc * 256;
  float* qb = q_buf + hc * 4096;
  const float* Trow = s_T + wave * 128 + l15;   // + mt*16 + tap offset

  // persistent per-mt state (statically indexed everywhere)
  f16x4 qf[4];
  f32x4 O[4];
  float L[4];
#pragma unroll
  for (int mt = 0; mt < 4; ++mt) {
    int m = mblock * 256 + wave * 64 + mt * 16 + l15;
#pragma unroll
    for (int j = 0; j < 4; ++j)
      qf[mt][j] = (_Float16)qb[(quad * 4 + j) * 4096 + m];  // B[c][m]
    O[mt][0] = 0.f; O[mt][1] = 0.f; O[mt][2] = 0.f; O[mt][3] = 0.f;
    L[mt] = 0.f;
  }

#pragma unroll 2
  for (int t = 0; t < 16; ++t) {
    // K frag: A[n][c]: n = t*16 + l15, c = quad*4+j  (f16 direct loads)
    f16x4 kf;
#pragma unroll
    for (int j = 0; j < 4; ++j)
      kf[j] = kb[(quad * 4 + j) * 256 + t * 16 + l15];
    // V frag: A[c][n]: c = l15, n = t*16 + quad*4+j -> contiguous 8B f16x4
    f16x4 vf = *(const f16x4*)(vb + l15 * 256 + t * 16 + quad * 4);

    f32x4 S[4];
#pragma unroll
    for (int mt = 0; mt < 4; ++mt) {
      f32x4 Z = {0.f, 0.f, 0.f, 0.f};
      S[mt] = __builtin_amdgcn_mfma_f32_16x16x16f16(kf, qf[mt], Z, 0, 0, 0);
    }

    f16x4 pf[4];
#pragma unroll
    for (int r = 0; r < 4; ++r) {
      int off = s_off[t * 16 + quad * 4 + r];     // broadcast b32
      float4 wt = s_wt[t * 16 + quad * 4 + r];    // broadcast b128
#pragma unroll
      for (int mt = 0; mt < 4; ++mt) {
        const float* p = Trow + mt * 16 + off;
        float bias = wt.x * p[0] + wt.y * p[1] + wt.z * p[128] + wt.w * p[129];
        float s = fmaf(S[mt][r], 0.25f, bias);
        float e = __expf(s);
        L[mt] += e;
        pf[mt][r] = (_Float16)e;
      }
    }
#pragma unroll
    for (int mt = 0; mt < 4; ++mt)
      O[mt] = __builtin_amdgcn_mfma_f32_16x16x16f16(vf, pf[mt], O[mt], 0, 0, 0);
  }

#pragma unroll
  for (int mt = 0; mt < 4; ++mt) {
    float Lm = L[mt];
    Lm += __shfl_xor(Lm, 16);
    Lm += __shfl_xor(Lm, 32);
    float rinv = 1.f / Lm;
    int m = mblock * 256 + wave * 64 + mt * 16 + l15;
#pragma unroll
    for (int r = 0; r < 4; ++r)
      qb[(quad * 4 + r) * 4096 + m] = O[mt][r] * rinv;  // in-place over q
  }
}

// ------------------- po conv, out[l][b][64+o][p] += sum_num conv + bias
// Round-7: og-split 8 (grid 2048, acc[8]). Level-2 blocks loop num in
// {1,2} (two passes, same acc), zero atomics. x re-reads are L2/L3.
__global__ __launch_bounds__(256) void k_po(
    const float* __restrict__ attn_buf, const float* __restrict__ po_w,
    const float* __restrict__ po_b, float* __restrict__ out) {
  int wg = blockIdx.x;              // l(2)<<10 | og(8)<<7 | b(8)<<4 | tile(16)
  int tile = wg & 15;
  int b = (wg >> 4) & 7;
  int og = (wg >> 7) & 7;
  int l = (wg >> 10) + 1;           // 1 or 2
  int px = tile * 256 + threadIdx.x;
  int nlo = (l == 1) ? 0 : 1;
  int nPasses = (l == 1) ? 1 : 2;

  float acc[8];
#pragma unroll
  for (int o = 0; o < 8; ++o) acc[o] = 0.f;

  for (int s = 0; s < nPasses; ++s) {
    int num = nlo + s;
    const float* abase = attn_buf + (num * 8 + b) * 64 * 4096 + px;
    const float* w = po_w + num * 4096 + og * 512;
#pragma unroll 8
    for (int c = 0; c < 64; ++c) {
      float xv = abase[c * 4096];   // coalesced, 8 in flight
#pragma unroll
      for (int o = 0; o < 8; ++o) acc[o] += w[o * 64 + c] * xv;  // s_loads
    }
  }

  float* ob = out + ((l * 8 + b) * 128 + 64 + og * 8) * 4096 + px;
#pragma unroll
  for (int o = 0; o < 8; ++o) {
    float bias = po_b[nlo * 64 + og * 8 + o];
    if (l == 2) bias += po_b[128 + og * 8 + o];
    ob[o * 4096] += acc[o] + bias;  // plain RMW, no atomics
  }
}

extern "C" void kernel_launch(void* const* d_in, const int* in_sizes, int n_in,
                              void* d_out, int out_size, void* d_ws,
                              size_t ws_size, hipStream_t stream) {
  const float* x0 = (const float*)d_in[0];
  const float* x1 = (const float*)d_in[1];
  const float* x2 = (const float*)d_in[2];
  const float* pq_w = (const float*)d_in[3];
  const float* pq_b = (const float*)d_in[4];
  const float* dw_w = (const float*)d_in[5];
  const float* dw_b = (const float*)d_in[6];
  const float* ln_g = (const float*)d_in[7];
  const float* ln_b = (const float*)d_in[8];
  const float* pw_w = (const float*)d_in[9];
  const float* pk_w = (const float*)d_in[10];
  const float* pk_b = (const float*)d_in[11];
  const float* pv_w = (const float*)d_in[12];
  const float* pv_b = (const float*)d_in[13];
  const float* po_w = (const float*)d_in[14];
  const float* po_b = (const float*)d_in[15];
  const float* rpe = (const float*)d_in[16];
  float* out = (float*)d_out;
  float* ws = (float*)d_ws;

  // ws layout (floats): q/attn (in-place) 6291456, pos 12288, xs 393216,
  // k 393216, v 393216 -> 29,933,568 bytes, IDENTICAL to round-0-proven size.
  // tpad (196608) aliases xs_buf: xs is dead after k_kv; k_padrpe runs after.
  // k/v buffers now hold f16 (half the region used; offsets unchanged).
  float* q_buf = ws;
  float* pos_buf = q_buf + 6291456;
  float* xs_buf = pos_buf + 12288;
  float* k_buf = xs_buf + 393216;
  float* v_buf = k_buf + 393216;
  float* tpad = xs_buf;
  _Float16* k16 = (_Float16*)k_buf;
  _Float16* v16 = (_Float16*)v_buf;

  hipLaunchKernelGGL(k_copy, dim3(12288), dim3(256), 0, stream, x0, x1, x2, out);
  hipLaunchKernelGGL(k_qconv, dim3(3072), dim3(256), 0, stream, x1, x2, pq_w,
                     pq_b, q_buf);
  hipLaunchKernelGGL(k_offset, dim3(24), dim3(256), 0, stream, q_buf, dw_w,
                     dw_b, ln_g, ln_b, pw_w, pos_buf);
  hipLaunchKernelGGL(k_sample, dim3(192), dim3(256), 0, stream, x0, x1,
                     pos_buf, xs_buf);
  hipLaunchKernelGGL(k_kv, dim3(384), dim3(256), 0, stream, xs_buf, pk_w, pk_b,
                     pv_w, pv_b, k16, v16);
  hipLaunchKernelGGL(k_padrpe, dim3(1536), dim3(128), 0, stream, rpe, tpad);
  hipLaunchKernelGGL(k_attn, dim3(1536), dim3(256), 0, stream, q_buf, k16,
                     v16, pos_buf, tpad);
  hipLaunchKernelGGL(k_po, dim3(2048), dim3(256), 0, stream, q_buf, po_w, po_b,
                     out);
}